// Round 1
// baseline (428.180 us; speedup 1.0000x reference)
//
#include <hip/hip_runtime.h>
#include <hip/hip_fp16.h>
#include <cstdint>
#include <cstddef>

#define M_DIM 8192
#define N_DIM 4096
#define K_DIM 4096

typedef int v4i __attribute__((ext_vector_type(4)));

// ---------------------------------------------------------------------------
// Pack kernel: int32 (harness-widened int8) -> int8, 16 elements per thread.
// ---------------------------------------------------------------------------
__global__ __launch_bounds__(256) void pack_i32_to_i8(const int* __restrict__ src,
                                                      uint8_t* __restrict__ dst,
                                                      int n16) {
    int i = blockIdx.x * 256 + threadIdx.x;
    if (i >= n16) return;
    const int4* s = (const int4*)src + (size_t)i * 4;
    int4 a = s[0], b = s[1], c = s[2], d = s[3];
    uint32_t p0 = (a.x & 0xff) | ((a.y & 0xff) << 8) | ((a.z & 0xff) << 16) | ((uint32_t)(a.w & 0xff) << 24);
    uint32_t p1 = (b.x & 0xff) | ((b.y & 0xff) << 8) | ((b.z & 0xff) << 16) | ((uint32_t)(b.w & 0xff) << 24);
    uint32_t p2 = (c.x & 0xff) | ((c.y & 0xff) << 8) | ((c.z & 0xff) << 16) | ((uint32_t)(c.w & 0xff) << 24);
    uint32_t p3 = (d.x & 0xff) | ((d.y & 0xff) << 8) | ((d.z & 0xff) << 16) | ((uint32_t)(d.w & 0xff) << 24);
    ((uint4*)dst)[i] = make_uint4(p0, p1, p2, p3);
}

// ---------------------------------------------------------------------------
// async global->LDS, 16B per lane (global_load_lds_dwordx4)
// ---------------------------------------------------------------------------
__device__ __forceinline__ void gload_lds16(const void* g, void* l) {
    __builtin_amdgcn_global_load_lds(
        (const __attribute__((address_space(1))) void*)g,
        (__attribute__((address_space(3))) void*)l,
        16, 0, 0);
}

// ---------------------------------------------------------------------------
// GEMM: C[m][n] = sum_k A[m][k]*W[n][k], int32 acc, fused dequant epilogue.
// 128x128 block tile, BK=64, 4 waves (2x2), each wave 64x64 via 4x4 MFMA
// tiles of mfma_i32_16x16x64_i8. m97-structure: global_load_lds staging,
// 2-barrier K-loop.
// ---------------------------------------------------------------------------
__global__ __launch_bounds__(256) void gemm_i8_dq(const int8_t* __restrict__ A,
                                                  const int8_t* __restrict__ W,
                                                  const float* __restrict__ sx,
                                                  const float* __restrict__ sw,
                                                  const float* __restrict__ bias,
                                                  float* __restrict__ out) {
    __shared__ int8_t sA[128 * 64];   // [row][k] row-major, 64B rows
    __shared__ int8_t sB[128 * 64];

    const int t    = threadIdx.x;
    const int lane = t & 63;
    const int wave = t >> 6;
    const int wm   = wave >> 1;       // 0..1
    const int wn   = wave & 1;        // 0..1
    const int bm   = blockIdx.y;      // 0..63
    const int bn   = blockIdx.x;      // 0..31

    // ---- staging addresses (each thread stages 16B x 4 issues per K-tile) ----
    const int srow = t >> 2;          // 0..63
    const int scol = (t & 3) * 16;    // 0,16,32,48
    const int8_t* gA0 = A + (size_t)(bm * 128 + srow) * K_DIM + scol;
    const int8_t* gA1 = A + (size_t)(bm * 128 + 64 + srow) * K_DIM + scol;
    const int8_t* gB0 = W + (size_t)(bn * 128 + srow) * K_DIM + scol;
    const int8_t* gB1 = W + (size_t)(bn * 128 + 64 + srow) * K_DIM + scol;
    int8_t* lA0 = &sA[t * 16];        // == srow*64 + scol  (lane-contiguous)
    int8_t* lA1 = &sA[4096 + t * 16];
    int8_t* lB0 = &sB[t * 16];
    int8_t* lB1 = &sB[4096 + t * 16];

    // ---- fragment read addresses ----
    // A frag (16x16x64): lane holds A[m = lane&15][k = (lane>>4)*16 + j], j=0..15
    const int frow_a = wm * 64 + (lane & 15);
    const int frow_b = wn * 64 + (lane & 15);
    const int koff   = (lane >> 4) * 16;

    v4i acc[4][4];
    const v4i vzero = {0, 0, 0, 0};
#pragma unroll
    for (int mi = 0; mi < 4; mi++)
#pragma unroll
        for (int ni = 0; ni < 4; ni++) acc[mi][ni] = vzero;

    for (int kt = 0; kt < K_DIM; kt += 64) {
        __syncthreads();              // previous tile's ds_reads done
        gload_lds16(gA0 + kt, lA0);
        gload_lds16(gA1 + kt, lA1);
        gload_lds16(gB0 + kt, lB0);
        gload_lds16(gB1 + kt, lB1);
        __syncthreads();              // drains vmcnt: staging complete

        v4i af[4], bf[4];
#pragma unroll
        for (int i = 0; i < 4; i++) {
            af[i] = *(const v4i*)(&sA[(frow_a + i * 16) * 64 + koff]);
            bf[i] = *(const v4i*)(&sB[(frow_b + i * 16) * 64 + koff]);
        }
#pragma unroll
        for (int mi = 0; mi < 4; mi++)
#pragma unroll
            for (int ni = 0; ni < 4; ni++)
                acc[mi][ni] = __builtin_amdgcn_mfma_i32_16x16x64_i8(
                    af[mi], bf[ni], acc[mi][ni], 0, 0, 0);
    }

    // ---- epilogue: C/D 16x16 layout: col = lane&15, row = (lane>>4)*4 + r ----
    const float DIVF = (float)(1.0 / (127.0 * 127.0));
    const int col0 = bn * 128 + wn * 64 + (lane & 15);
    const int row0 = bm * 128 + wm * 64 + (lane >> 4) * 4;

    float swv[4], bv[4];
#pragma unroll
    for (int ni = 0; ni < 4; ni++) {
        swv[ni] = sw[col0 + ni * 16];
        bv[ni]  = bias[col0 + ni * 16];
    }

#pragma unroll
    for (int mi = 0; mi < 4; mi++) {
#pragma unroll
        for (int r = 0; r < 4; r++) {
            const int row = row0 + mi * 16 + r;
            const float xs = sx[row];
#pragma unroll
            for (int ni = 0; ni < 4; ni++) {
                // numpy op order: ((acc_f * DIV) * sx) * sw + bias, no fma contraction
                float v = __fmul_rn((float)acc[mi][ni][r], DIVF);
                v = __fmul_rn(v, xs);
                v = __fmul_rn(v, swv[ni]);
                v = __fadd_rn(v, bv[ni]);
                // reference casts to fp16; emulate the rounding, store as f32
                out[(size_t)row * N_DIM + col0 + ni * 16] = __half2float(__float2half(v));
            }
        }
    }
}

extern "C" void kernel_launch(void* const* d_in, const int* in_sizes, int n_in,
                              void* d_out, int out_size, void* d_ws, size_t ws_size,
                              hipStream_t stream) {
    const int*   x_i32 = (const int*)d_in[0];      // [M,K] int (widened int8)
    const float* sx    = (const float*)d_in[1];    // [M] f32
    const int*   w_i32 = (const int*)d_in[2];      // [N,K] int (widened int8)
    const float* sw    = (const float*)d_in[3];    // [N] f32
    const float* bias  = (const float*)d_in[4];    // [N] f32 (widened fp16)
    float* out = (float*)d_out;                    // [M,N] f32 (widened fp16)

    uint8_t* xb = (uint8_t*)d_ws;                          // 32 MB packed x
    uint8_t* wb = (uint8_t*)d_ws + (size_t)M_DIM * K_DIM;  // 16 MB packed w

    const int nx16 = (M_DIM * K_DIM) / 16;  // 2,097,152
    const int nw16 = (N_DIM * K_DIM) / 16;  // 1,048,576
    pack_i32_to_i8<<<(nx16 + 255) / 256, 256, 0, stream>>>(x_i32, xb, nx16);
    pack_i32_to_i8<<<(nw16 + 255) / 256, 256, 0, stream>>>(w_i32, wb, nw16);

    dim3 grid(N_DIM / 128, M_DIM / 128);  // (32, 64)
    gemm_i8_dq<<<grid, 256, 0, stream>>>((const int8_t*)xb, (const int8_t*)wb,
                                         sx, sw, bias, out);
}